// Round 1
// 1434.625 us; speedup vs baseline: 1.0090x; 1.0090x over previous
//
#include <hip/hip_runtime.h>
#include <math.h>

#define HIDDEN 1024
#define NBATCH 4
#define SEQ    4096
#define NKQ    4096

typedef unsigned short us;
typedef __attribute__((ext_vector_type(8))) short short8;
typedef __attribute__((ext_vector_type(4))) float f32x4;

// round-to-nearest-even fp32 -> bf16 bits
__device__ __forceinline__ us f2b(float f) {
    unsigned u = __float_as_uint(f);
    return (us)((u + 0x7fffu + ((u >> 16) & 1u)) >> 16);
}

// async 16B global -> LDS (wave-uniform base + lane*16 layout required)
__device__ __forceinline__ void glds16(const void* g, void* l) {
    __builtin_amdgcn_global_load_lds(
        (const __attribute__((address_space(1))) unsigned*)g,
        (__attribute__((address_space(3))) unsigned*)l, 16, 0, 0);
}

// ---------------------------------------------------------------------------
// NT GEMM, bf16 MFMA 16x16x32: C[m,n] = scale * sum_k A[m,k]*B[n,k] (+bias[n])
// A: fp32 (convert-on-stage) or bf16 (global_load_lds). B: bf16 [N,K].
// 128x128 tile, BK=32, 256 threads = 4 waves, each wave a 64x64 subtile.
// SWZ: XCD-bijective block remap so blocks sharing an A panel (same y, all x)
//      are consecutive on one XCD's L2 instead of round-robined across 8.
// ---------------------------------------------------------------------------
template <bool A_IS_F32, bool HAS_BIAS, bool OUT_BF16, bool SWZ>
__global__ __launch_bounds__(256) void gemm_nt(
    const void* __restrict__ Av, const us* __restrict__ B,
    const float* __restrict__ bias, void* __restrict__ Cv,
    int M, int N, int K, long sA, long sB, long sC, float scale)
{
    __shared__ us As[128 * 32];   // 8 KB, row-major [row][k]
    __shared__ us Bs[128 * 32];   // 8 KB

    int bxi = blockIdx.x, byi = blockIdx.y, bzi = blockIdx.z;
    if (SWZ) {
        const int gx = gridDim.x, gy = gridDim.y;
        const int n  = gx * gy * gridDim.z;   // must be % 8 == 0
        int lid = bxi + gx * (byi + gy * bzi);
        int nl  = (lid & 7) * (n >> 3) + (lid >> 3);
        bxi = nl % gx;
        nl /= gx;
        byi = nl % gy;
        bzi = nl / gy;
    }

    const int tid = threadIdx.x;
    const int bm = byi * 128;
    const int bn = bxi * 128;
    const int lane = tid & 63;
    const int wv   = tid >> 6;
    const int wm = (wv >> 1) * 64;       // wave subtile origin
    const int wn = (wv & 1) * 64;
    const int fm = lane & 15;            // fragment row/col within 16
    const int q8 = (lane >> 4) * 8;      // fragment k offset

    // B staging: thread t loads 8 bf16 of row (bn + t>>2), chunk t&3; 2 issues
    const us* Bg = B + (long)bzi * sB + (long)(bn + (tid >> 2)) * K + (tid & 3) * 8;
    us* BsT = &Bs[tid * 8];

    // A staging pointers
    const us*    Agb = nullptr;
    const float* Agf = nullptr;
    us* AsTb = nullptr;
    us* AsTf = nullptr;
    if (A_IS_F32) {
        Agf  = (const float*)Av + (long)bzi * sA + (long)(bm + (tid >> 3)) * K + (tid & 7) * 4;
        AsTf = &As[(tid >> 3) * 32 + (tid & 7) * 4];
    } else {
        Agb  = (const us*)Av + (long)bzi * sA + (long)(bm + (tid >> 2)) * K + (tid & 3) * 8;
        AsTb = &As[tid * 8];
    }

    f32x4 acc[4][4];
#pragma unroll
    for (int i = 0; i < 4; i++)
#pragma unroll
        for (int j = 0; j < 4; j++)
            acc[i][j] = (f32x4){0.f, 0.f, 0.f, 0.f};

    for (int kt = 0; kt < K; kt += 32) {
        float4 fa[4];
        if (A_IS_F32) {
#pragma unroll
            for (int e = 0; e < 4; e++)
                fa[e] = *(const float4*)(Agf + (long)(32 * e) * K + kt);
        }
        __syncthreads();  // previous iteration's frag reads complete
        // B tile via async DMA
        glds16(Bg + kt, BsT);
        glds16(Bg + kt + (long)64 * K, BsT + 2048);
        if (A_IS_F32) {
#pragma unroll
            for (int e = 0; e < 4; e++) {
                ushort4 h;
                h.x = f2b(fa[e].x); h.y = f2b(fa[e].y);
                h.z = f2b(fa[e].z); h.w = f2b(fa[e].w);
                *(ushort4*)(AsTf + 1024 * e) = h;
            }
        } else {
            glds16(Agb + kt, AsTb);
            glds16(Agb + kt + (long)64 * K, AsTb + 2048);
        }
        __syncthreads();  // staging complete

        short8 af[4], bf[4];
#pragma unroll
        for (int mi = 0; mi < 4; mi++)
            af[mi] = *(const short8*)&As[(wm + mi * 16 + fm) * 32 + q8];
#pragma unroll
        for (int ni = 0; ni < 4; ni++)
            bf[ni] = *(const short8*)&Bs[(wn + ni * 16 + fm) * 32 + q8];
#pragma unroll
        for (int mi = 0; mi < 4; mi++)
#pragma unroll
            for (int ni = 0; ni < 4; ni++)
                acc[mi][ni] = __builtin_amdgcn_mfma_f32_16x16x32_bf16(
                    af[mi], bf[ni], acc[mi][ni], 0, 0, 0);
    }

    // epilogue: C/D layout col=lane&15, row=(lane>>4)*4+reg
    const int er4 = (lane >> 4) * 4;
#pragma unroll
    for (int ni = 0; ni < 4; ni++) {
        const int col = bn + wn + ni * 16 + fm;
        const float bv = HAS_BIAS ? bias[col] : 0.0f;
#pragma unroll
        for (int mi = 0; mi < 4; mi++) {
#pragma unroll
            for (int r = 0; r < 4; r++) {
                const int row = bm + wm + mi * 16 + er4 + r;
                const float v = acc[mi][ni][r] * scale + bv;
                const long idx = (long)bzi * sC + (long)row * N + col;
                if (OUT_BF16) ((us*)Cv)[idx] = f2b(v);
                else          ((float*)Cv)[idx] = v;
            }
        }
    }
}

// ---------------------------------------------------------------------------
// fp32 -> bf16 elementwise (weights)
// ---------------------------------------------------------------------------
__global__ __launch_bounds__(256) void f2b_kernel(const float* __restrict__ in,
                                                  us* __restrict__ out, int n)
{
    const int i = (blockIdx.x * 256 + threadIdx.x) * 4;
    if (i < n) {
        const float4 f = *(const float4*)&in[i];
        ushort4 h;
        h.x = f2b(f.x); h.y = f2b(f.y); h.z = f2b(f.z); h.w = f2b(f.w);
        *(ushort4*)&out[i] = h;
    }
}

// ---------------------------------------------------------------------------
// bf16 transpose: in [SEQ][HIDDEN] -> out [HIDDEN][SEQ], per batch (z)
// ---------------------------------------------------------------------------
__global__ __launch_bounds__(256) void transpose_b_kernel(const us* __restrict__ in,
                                                          us* __restrict__ out)
{
    __shared__ us tile[64][72];
    const int t = threadIdx.x;
    const long ib = (long)blockIdx.z * SEQ * HIDDEN;
    const long ob = (long)blockIdx.z * (long)HIDDEN * SEQ;
    const int s0 = blockIdx.y * 64, h0 = blockIdx.x * 64;
    const int r = t >> 3, c = (t & 7) * 8;
#pragma unroll
    for (int e = 0; e < 2; e++) {
        const int rr = r + 32 * e;
        const uint4 v = *(const uint4*)&in[ib + (long)(s0 + rr) * HIDDEN + h0 + c];
        us* dst = &tile[rr][c];
        ((uint*)dst)[0] = v.x; ((uint*)dst)[1] = v.y;
        ((uint*)dst)[2] = v.z; ((uint*)dst)[3] = v.w;
    }
    __syncthreads();
#pragma unroll
    for (int e = 0; e < 2; e++) {
        const int rr = r + 32 * e;   // h index within tile
        us vals[8];
#pragma unroll
        for (int j = 0; j < 8; j++) vals[j] = tile[c + j][rr];
        *(uint4*)&out[ob + (long)(h0 + rr) * SEQ + s0 + c] = *(uint4*)vals;
    }
}

// ---------------------------------------------------------------------------
// row softmax in place: a is [rows][SEQ] fp32, one block per row.
// Also emits a bf16 copy of the normalized row (PV GEMM A operand).
// ---------------------------------------------------------------------------
__global__ __launch_bounds__(256) void softmax_rows_kernel(float* __restrict__ a,
                                                           us* __restrict__ ab)
{
    const long roff = ((long)blockIdx.y * NKQ + blockIdx.x) * SEQ;
    float* row = a + roff;
    us* rowb = ab + roff;
    const int t = threadIdx.x;
    const int lane = t & 63, wv = t >> 6;
    __shared__ float red[8];

    float4 x[4];
    float m = -INFINITY;
#pragma unroll
    for (int e = 0; e < 4; e++) {
        x[e] = *(const float4*)&row[t * 4 + 1024 * e];
        m = fmaxf(m, fmaxf(fmaxf(x[e].x, x[e].y), fmaxf(x[e].z, x[e].w)));
    }
#pragma unroll
    for (int o = 32; o; o >>= 1) m = fmaxf(m, __shfl_xor(m, o));
    if (lane == 0) red[wv] = m;
    __syncthreads();
    m = fmaxf(fmaxf(red[0], red[1]), fmaxf(red[2], red[3]));

    float s = 0.f;
#pragma unroll
    for (int e = 0; e < 4; e++) {
        x[e].x = __expf(x[e].x - m); x[e].y = __expf(x[e].y - m);
        x[e].z = __expf(x[e].z - m); x[e].w = __expf(x[e].w - m);
        s += x[e].x + x[e].y + x[e].z + x[e].w;
    }
#pragma unroll
    for (int o = 32; o; o >>= 1) s += __shfl_xor(s, o);
    if (lane == 0) red[4 + wv] = s;
    __syncthreads();
    s = red[4] + red[5] + red[6] + red[7];

    const float inv = 1.0f / s;
#pragma unroll
    for (int e = 0; e < 4; e++) {
        x[e].x *= inv; x[e].y *= inv; x[e].z *= inv; x[e].w *= inv;
        *(float4*)&row[t * 4 + 1024 * e] = x[e];
        ushort4 h;
        h.x = f2b(x[e].x); h.y = f2b(x[e].y);
        h.z = f2b(x[e].z); h.w = f2b(x[e].w);
        *(ushort4*)&rowb[t * 4 + 1024 * e] = h;
    }
}

// ---------------------------------------------------------------------------
// in-place fp32 square transpose (4096x4096 per batch) via 64x64 tile pairs
// ---------------------------------------------------------------------------
__global__ __launch_bounds__(256) void transpose_f32_ip_kernel(float* __restrict__ a)
{
    const int ti = blockIdx.y, tj = blockIdx.x;
    if (tj < ti) return;
    float* base = a + (long)blockIdx.z * NKQ * SEQ;
    __shared__ float ta[64][65];
    __shared__ float tb[64][65];
    const int t = threadIdx.x, r = t >> 4, c = (t & 15) * 4;
    const bool diag = (ti == tj);
#pragma unroll
    for (int e = 0; e < 4; e++) {
        const int rr = r + 16 * e;
        const float4 va = *(const float4*)&base[(long)(ti * 64 + rr) * 4096 + tj * 64 + c];
        ta[rr][c] = va.x; ta[rr][c + 1] = va.y; ta[rr][c + 2] = va.z; ta[rr][c + 3] = va.w;
        if (!diag) {
            const float4 vb = *(const float4*)&base[(long)(tj * 64 + rr) * 4096 + ti * 64 + c];
            tb[rr][c] = vb.x; tb[rr][c + 1] = vb.y; tb[rr][c + 2] = vb.z; tb[rr][c + 3] = vb.w;
        }
    }
    __syncthreads();
#pragma unroll
    for (int e = 0; e < 4; e++) {
        const int rr = r + 16 * e;
        float4 w;
        w.x = ta[c][rr]; w.y = ta[c + 1][rr]; w.z = ta[c + 2][rr]; w.w = ta[c + 3][rr];
        *(float4*)&base[(long)(tj * 64 + rr) * 4096 + ti * 64 + c] = w;
        if (!diag) {
            float4 u;
            u.x = tb[c][rr]; u.y = tb[c + 1][rr]; u.z = tb[c + 2][rr]; u.w = tb[c + 3][rr];
            *(float4*)&base[(long)(ti * 64 + rr) * 4096 + tj * 64 + c] = u;
        }
    }
}

// ---------------------------------------------------------------------------
extern "C" void kernel_launch(void* const* d_in, const int* in_sizes, int n_in,
                              void* d_out, int out_size, void* d_ws, size_t ws_size,
                              hipStream_t stream)
{
    const float* queries = (const float*)d_in[0];
    const float* keys    = (const float*)d_in[1];
    const float* values  = (const float*)d_in[2];
    const float* Wq = (const float*)d_in[3]; const float* bq = (const float*)d_in[4];
    const float* Wk = (const float*)d_in[5]; const float* bk = (const float*)d_in[6];
    const float* Wv = (const float*)d_in[7]; const float* bv = (const float*)d_in[8];

    float* ctx  = (float*)d_out;                       // [B][KQ][H]
    float* attn = ctx + (long)NBATCH * NKQ * HIDDEN;   // [B][KQ][S] then transposed in place

    // Workspace layout (160 MB total):
    //   [0,32)    vT_b   [B][H][S] bf16         (live through PV)
    //   [32,64)   q_b    [B][KQ][H] bf16        (dead after QK^T)
    //   [64,96)   k_b    [B][S][H] bf16         (dead after QK^T)
    //   [96,128)  v_b    [B][S][H] bf16         (dead after transpose_b)
    //   [128,134) Wqb/Wkb/Wvb bf16              (dead after projections)
    //   [32,160)  attn_b [B][KQ][S] bf16        (written by softmax; aliases
    //             q_b/k_b/v_b/W*b, all dead by then)
    char* ws = (char*)d_ws;
    us* vT_b = (us*)(ws);
    us* q_b  = (us*)(ws + (size_t)32  * 1024 * 1024);
    us* k_b  = (us*)(ws + (size_t)64  * 1024 * 1024);
    us* v_b  = (us*)(ws + (size_t)96  * 1024 * 1024);
    us* Wqb  = (us*)(ws + (size_t)128 * 1024 * 1024);
    us* Wkb  = Wqb + (size_t)HIDDEN * HIDDEN;
    us* Wvb  = Wkb + (size_t)HIDDEN * HIDDEN;
    us* attn_b = (us*)(ws + (size_t)32 * 1024 * 1024);

    const dim3 blk(256);
    const int nW = HIDDEN * HIDDEN;

    // weights -> bf16
    f2b_kernel<<<dim3(nW / 1024), blk, 0, stream>>>(Wq, Wqb, nW);
    f2b_kernel<<<dim3(nW / 1024), blk, 0, stream>>>(Wk, Wkb, nW);
    f2b_kernel<<<dim3(nW / 1024), blk, 0, stream>>>(Wv, Wvb, nW);

    // projections: [16384 x 1024] = fp32 in @ bf16 W^T + bias -> bf16
    gemm_nt<true, true, true, false><<<dim3(HIDDEN / 128, (NBATCH * NKQ) / 128, 1), blk, 0, stream>>>(
        queries, Wqb, bq, q_b, NBATCH * NKQ, HIDDEN, HIDDEN, 0, 0, 0, 1.0f);
    gemm_nt<true, true, true, false><<<dim3(HIDDEN / 128, (NBATCH * SEQ) / 128, 1), blk, 0, stream>>>(
        keys, Wkb, bk, k_b, NBATCH * SEQ, HIDDEN, HIDDEN, 0, 0, 0, 1.0f);
    gemm_nt<true, true, true, false><<<dim3(HIDDEN / 128, (NBATCH * SEQ) / 128, 1), blk, 0, stream>>>(
        values, Wvb, bv, v_b, NBATCH * SEQ, HIDDEN, HIDDEN, 0, 0, 0, 1.0f);

    // v_b [S][H] -> vT_b [H][S]
    transpose_b_kernel<<<dim3(HIDDEN / 64, SEQ / 64, NBATCH), blk, 0, stream>>>(v_b, vT_b);

    // scoresT[b][kq][s] = (1/32) * q_b[kq,:] . k_b[s,:]   -> attn region (fp32)
    gemm_nt<false, false, false, false><<<dim3(SEQ / 128, NKQ / 128, NBATCH), blk, 0, stream>>>(
        q_b, k_b, nullptr, attn, NKQ, SEQ, HIDDEN,
        (long)NKQ * HIDDEN, (long)SEQ * HIDDEN, (long)NKQ * SEQ, 0.03125f);

    // softmax over s (contiguous rows): fp32 in place + bf16 copy for PV
    softmax_rows_kernel<<<dim3(NKQ, NBATCH), blk, 0, stream>>>(attn, attn_b);

    // context[b][kq][h] = sum_s attn_b[kq,s] * vT_b[h,s]  (bf16 A, XCD swizzle)
    gemm_nt<false, false, false, true><<<dim3(HIDDEN / 128, NKQ / 128, NBATCH), blk, 0, stream>>>(
        attn_b, vT_b, nullptr, ctx, NKQ, HIDDEN, SEQ,
        (long)NKQ * SEQ, (long)HIDDEN * SEQ, (long)NKQ * HIDDEN, 1.0f);

    // attn [B][KQ][S] -> [B][S][KQ] in place
    transpose_f32_ip_kernel<<<dim3(64, 64, NBATCH), blk, 0, stream>>>(attn);
}

// Round 2
// 1285.246 us; speedup vs baseline: 1.1263x; 1.1162x over previous
//
#include <hip/hip_runtime.h>
#include <math.h>

#define HIDDEN 1024
#define NBATCH 4
#define SEQ    4096
#define NKQ    4096

typedef unsigned short us;
typedef __attribute__((ext_vector_type(8))) short short8;
typedef __attribute__((ext_vector_type(4))) float f32x4;

// round-to-nearest-even fp32 -> bf16 bits
__device__ __forceinline__ us f2b(float f) {
    unsigned u = __float_as_uint(f);
    return (us)((u + 0x7fffu + ((u >> 16) & 1u)) >> 16);
}

// async 16B global -> LDS (wave-uniform base + lane*16 layout required)
__device__ __forceinline__ void glds16(const void* g, void* l) {
    __builtin_amdgcn_global_load_lds(
        (const __attribute__((address_space(1))) unsigned*)g,
        (__attribute__((address_space(3))) unsigned*)l, 16, 0, 0);
}

// ---------------------------------------------------------------------------
// 256x256 / BK=64 / 8-wave phase-split NT GEMM (bf16 in, fp32 out).
// C[m,n] = scale * sum_k A[m,k]*B[n,k].
// - 512 threads = 8 waves as 2(M) x 4(N); per-wave output 128x64 (acc[8][4]).
// - LDS 128 KiB: double-buffered A[256][64] + B[256][64] bf16.
// - Per K-tile: 4 phases x {12 ds_read_b128, 2 global_load_lds prefetch,
//   s_barrier, 16 MFMA (setprio-wrapped), s_barrier}. vmcnt(0) only at the
//   K-tile boundary (loads stay in flight across the 4 phases).
// - T2 XOR swizzle (16B granule ^ (row&7)) applied as pre-swizzled GLOBAL
//   source + swizzled ds_read address; LDS dest stays linear (glds rule).
// - XCD-bijective block swizzle (grid size % 8 == 0 at all call sites).
// ---------------------------------------------------------------------------
__global__ __launch_bounds__(512, 2) void gemm_nt_256(
    const us* __restrict__ A, const us* __restrict__ B, float* __restrict__ C,
    int M, int N, int K, long sA, long sB, long sC, float scale)
{
    __shared__ us As[2][256 * 64];   // 32 KB each
    __shared__ us Bs[2][256 * 64];

    // XCD-bijective swizzle: HW id stride-8 -> contiguous logical ids per XCD
    int bxi = blockIdx.x, byi = blockIdx.y, bzi = blockIdx.z;
    {
        const int gx = gridDim.x, gy = gridDim.y;
        const int n  = gx * gy * gridDim.z;   // % 8 == 0 required
        int lid = bxi + gx * (byi + gy * bzi);
        int nl  = (lid & 7) * (n >> 3) + (lid >> 3);
        bxi = nl % gx;  nl /= gx;
        byi = nl % gy;  bzi = nl / gy;
    }

    const int tid  = threadIdx.x;
    const int lane = tid & 63;
    const int wv   = tid >> 6;            // 0..7
    const int wr   = wv >> 2;             // 0..1 : M half
    const int wc   = wv & 3;              // 0..3 : N quarter
    const int fm   = lane & 15;
    const int l16  = lane >> 4;           // 0..3
    const int bm   = byi * 256;
    const int bn   = bxi * 256;

    // staging: thread t -> row (t>>3) within each 64-row issue, 16B granule
    // slot (t&7); global source pre-swizzled so LDS slot g holds global
    // granule g ^ (row&7).
    const int rA  = tid >> 3;                       // 0..63
    const int gsw = (tid & 7) ^ (rA & 7);           // swizzled source granule
    const us* Ag = A + (long)bzi * sA + (long)(bm + rA) * K + gsw * 8;
    const us* Bg = B + (long)bzi * sB + (long)(bn + rA) * K + gsw * 8;
    us* AsT0 = &As[0][tid * 8];  us* BsT0 = &Bs[0][tid * 8];
    us* AsT1 = &As[1][tid * 8];  us* BsT1 = &Bs[1][tid * 8];

    f32x4 acc[8][4];
#pragma unroll
    for (int i = 0; i < 8; i++)
#pragma unroll
        for (int j = 0; j < 4; j++)
            acc[i][j] = (f32x4){0.f, 0.f, 0.f, 0.f};

    // prologue: stage full tile 0, drain, barrier
#pragma unroll
    for (int j = 0; j < 4; j++) {
        glds16(Ag + (long)(j * 64) * K, AsT0 + j * 4096);
        glds16(Bg + (long)(j * 64) * K, BsT0 + j * 4096);
    }
    asm volatile("s_waitcnt vmcnt(0)" ::: "memory");
    __builtin_amdgcn_s_barrier();

    const int xr = (fm & 7) * 8;   // read-side XOR (us units; (a^b)*8==(a*8)^(b*8))

    int cur = 0;
    for (int kt = 0; kt < K; kt += 64) {
        const int ktn = kt + 64;
        const bool pf = ktn < K;
        const us* Asb = As[cur];
        const us* Bsb = Bs[cur];
        us* AsTn = cur ? AsT0 : AsT1;
        us* BsTn = cur ? BsT0 : BsT1;

#pragma unroll
        for (int q = 0; q < 4; q++) {
            const int mh = q & 1, nh = q >> 1;
            short8 a[4][2], b[2][2];
#pragma unroll
            for (int m = 0; m < 4; m++) {
                const int arow = wr * 128 + (mh * 4 + m) * 16 + fm;
#pragma unroll
                for (int kk = 0; kk < 2; kk++)
                    a[m][kk] = *(const short8*)&Asb[arow * 64 + (((kk * 4 + l16) * 8) ^ xr)];
            }
#pragma unroll
            for (int n = 0; n < 2; n++) {
                const int brow = wc * 64 + (nh * 2 + n) * 16 + fm;
#pragma unroll
                for (int kk = 0; kk < 2; kk++)
                    b[n][kk] = *(const short8*)&Bsb[brow * 64 + (((kk * 4 + l16) * 8) ^ xr)];
            }
            if (pf) {   // prefetch chunk q of next K-tile (stays in flight)
                glds16(Ag + (long)(q * 64) * K + ktn, AsTn + q * 4096);
                glds16(Bg + (long)(q * 64) * K + ktn, BsTn + q * 4096);
            }
            __builtin_amdgcn_s_barrier();
            __builtin_amdgcn_s_setprio(1);
#pragma unroll
            for (int m = 0; m < 4; m++)
#pragma unroll
                for (int n = 0; n < 2; n++)
#pragma unroll
                    for (int kk = 0; kk < 2; kk++)
                        acc[mh * 4 + m][nh * 2 + n] = __builtin_amdgcn_mfma_f32_16x16x32_bf16(
                            a[m][kk], b[n][kk], acc[mh * 4 + m][nh * 2 + n], 0, 0, 0);
            __builtin_amdgcn_s_setprio(0);
            if (q < 3) {
                __builtin_amdgcn_s_barrier();
            } else {
                asm volatile("s_waitcnt vmcnt(0)" ::: "memory");
                __builtin_amdgcn_s_barrier();
            }
        }
        cur ^= 1;
    }

    // epilogue: C/D layout col=lane&15, row=(lane>>4)*4+reg
    const int er4 = l16 * 4;
#pragma unroll
    for (int ni = 0; ni < 4; ni++) {
        const int col = bn + wc * 64 + ni * 16 + fm;
#pragma unroll
        for (int mi = 0; mi < 8; mi++) {
            const int row = bm + wr * 128 + mi * 16 + er4;
#pragma unroll
            for (int r = 0; r < 4; r++)
                C[(long)bzi * sC + (long)(row + r) * N + col] = acc[mi][ni][r] * scale;
        }
    }
}

// ---------------------------------------------------------------------------
// NT GEMM, bf16 MFMA 16x16x32 (legacy 128x128): used for the fp32-A projections
// ---------------------------------------------------------------------------
template <bool A_IS_F32, bool HAS_BIAS, bool OUT_BF16, bool SWZ>
__global__ __launch_bounds__(256) void gemm_nt(
    const void* __restrict__ Av, const us* __restrict__ B,
    const float* __restrict__ bias, void* __restrict__ Cv,
    int M, int N, int K, long sA, long sB, long sC, float scale)
{
    __shared__ us As[128 * 32];   // 8 KB, row-major [row][k]
    __shared__ us Bs[128 * 32];   // 8 KB

    int bxi = blockIdx.x, byi = blockIdx.y, bzi = blockIdx.z;
    if (SWZ) {
        const int gx = gridDim.x, gy = gridDim.y;
        const int n  = gx * gy * gridDim.z;   // must be % 8 == 0
        int lid = bxi + gx * (byi + gy * bzi);
        int nl  = (lid & 7) * (n >> 3) + (lid >> 3);
        bxi = nl % gx;
        nl /= gx;
        byi = nl % gy;
        bzi = nl / gy;
    }

    const int tid = threadIdx.x;
    const int bm = byi * 128;
    const int bn = bxi * 128;
    const int lane = tid & 63;
    const int wv   = tid >> 6;
    const int wm = (wv >> 1) * 64;       // wave subtile origin
    const int wn = (wv & 1) * 64;
    const int fm = lane & 15;            // fragment row/col within 16
    const int q8 = (lane >> 4) * 8;      // fragment k offset

    // B staging: thread t loads 8 bf16 of row (bn + t>>2), chunk t&3; 2 issues
    const us* Bg = B + (long)bzi * sB + (long)(bn + (tid >> 2)) * K + (tid & 3) * 8;
    us* BsT = &Bs[tid * 8];

    // A staging pointers
    const us*    Agb = nullptr;
    const float* Agf = nullptr;
    us* AsTb = nullptr;
    us* AsTf = nullptr;
    if (A_IS_F32) {
        Agf  = (const float*)Av + (long)bzi * sA + (long)(bm + (tid >> 3)) * K + (tid & 7) * 4;
        AsTf = &As[(tid >> 3) * 32 + (tid & 7) * 4];
    } else {
        Agb  = (const us*)Av + (long)bzi * sA + (long)(bm + (tid >> 2)) * K + (tid & 3) * 8;
        AsTb = &As[tid * 8];
    }

    f32x4 acc[4][4];
#pragma unroll
    for (int i = 0; i < 4; i++)
#pragma unroll
        for (int j = 0; j < 4; j++)
            acc[i][j] = (f32x4){0.f, 0.f, 0.f, 0.f};

    for (int kt = 0; kt < K; kt += 32) {
        float4 fa[4];
        if (A_IS_F32) {
#pragma unroll
            for (int e = 0; e < 4; e++)
                fa[e] = *(const float4*)(Agf + (long)(32 * e) * K + kt);
        }
        __syncthreads();  // previous iteration's frag reads complete
        // B tile via async DMA
        glds16(Bg + kt, BsT);
        glds16(Bg + kt + (long)64 * K, BsT + 2048);
        if (A_IS_F32) {
#pragma unroll
            for (int e = 0; e < 4; e++) {
                ushort4 h;
                h.x = f2b(fa[e].x); h.y = f2b(fa[e].y);
                h.z = f2b(fa[e].z); h.w = f2b(fa[e].w);
                *(ushort4*)(AsTf + 1024 * e) = h;
            }
        } else {
            glds16(Agb + kt, AsTb);
            glds16(Agb + kt + (long)64 * K, AsTb + 2048);
        }
        __syncthreads();  // staging complete

        short8 af[4], bf[4];
#pragma unroll
        for (int mi = 0; mi < 4; mi++)
            af[mi] = *(const short8*)&As[(wm + mi * 16 + fm) * 32 + q8];
#pragma unroll
        for (int ni = 0; ni < 4; ni++)
            bf[ni] = *(const short8*)&Bs[(wn + ni * 16 + fm) * 32 + q8];
#pragma unroll
        for (int mi = 0; mi < 4; mi++)
#pragma unroll
            for (int ni = 0; ni < 4; ni++)
                acc[mi][ni] = __builtin_amdgcn_mfma_f32_16x16x32_bf16(
                    af[mi], bf[ni], acc[mi][ni], 0, 0, 0);
    }

    // epilogue: C/D layout col=lane&15, row=(lane>>4)*4+reg
    const int er4 = (lane >> 4) * 4;
#pragma unroll
    for (int ni = 0; ni < 4; ni++) {
        const int col = bn + wn + ni * 16 + fm;
        const float bv = HAS_BIAS ? bias[col] : 0.0f;
#pragma unroll
        for (int mi = 0; mi < 4; mi++) {
#pragma unroll
            for (int r = 0; r < 4; r++) {
                const int row = bm + wm + mi * 16 + er4 + r;
                const float v = acc[mi][ni][r] * scale + bv;
                const long idx = (long)bzi * sC + (long)row * N + col;
                if (OUT_BF16) ((us*)Cv)[idx] = f2b(v);
                else          ((float*)Cv)[idx] = v;
            }
        }
    }
}

// ---------------------------------------------------------------------------
// fp32 -> bf16 elementwise (weights)
// ---------------------------------------------------------------------------
__global__ __launch_bounds__(256) void f2b_kernel(const float* __restrict__ in,
                                                  us* __restrict__ out, int n)
{
    const int i = (blockIdx.x * 256 + threadIdx.x) * 4;
    if (i < n) {
        const float4 f = *(const float4*)&in[i];
        ushort4 h;
        h.x = f2b(f.x); h.y = f2b(f.y); h.z = f2b(f.z); h.w = f2b(f.w);
        *(ushort4*)&out[i] = h;
    }
}

// ---------------------------------------------------------------------------
// bf16 transpose: in [SEQ][HIDDEN] -> out [HIDDEN][SEQ], per batch (z)
// ---------------------------------------------------------------------------
__global__ __launch_bounds__(256) void transpose_b_kernel(const us* __restrict__ in,
                                                          us* __restrict__ out)
{
    __shared__ us tile[64][72];
    const int t = threadIdx.x;
    const long ib = (long)blockIdx.z * SEQ * HIDDEN;
    const long ob = (long)blockIdx.z * (long)HIDDEN * SEQ;
    const int s0 = blockIdx.y * 64, h0 = blockIdx.x * 64;
    const int r = t >> 3, c = (t & 7) * 8;
#pragma unroll
    for (int e = 0; e < 2; e++) {
        const int rr = r + 32 * e;
        const uint4 v = *(const uint4*)&in[ib + (long)(s0 + rr) * HIDDEN + h0 + c];
        us* dst = &tile[rr][c];
        ((uint*)dst)[0] = v.x; ((uint*)dst)[1] = v.y;
        ((uint*)dst)[2] = v.z; ((uint*)dst)[3] = v.w;
    }
    __syncthreads();
#pragma unroll
    for (int e = 0; e < 2; e++) {
        const int rr = r + 32 * e;   // h index within tile
        us vals[8];
#pragma unroll
        for (int j = 0; j < 8; j++) vals[j] = tile[c + j][rr];
        *(uint4*)&out[ob + (long)(h0 + rr) * SEQ + s0 + c] = *(uint4*)vals;
    }
}

// ---------------------------------------------------------------------------
// row softmax in place: a is [rows][SEQ] fp32, one block per row.
// Also emits a bf16 copy of the normalized row (PV GEMM A operand).
// ---------------------------------------------------------------------------
__global__ __launch_bounds__(256) void softmax_rows_kernel(float* __restrict__ a,
                                                           us* __restrict__ ab)
{
    const long roff = ((long)blockIdx.y * NKQ + blockIdx.x) * SEQ;
    float* row = a + roff;
    us* rowb = ab + roff;
    const int t = threadIdx.x;
    const int lane = t & 63, wv = t >> 6;
    __shared__ float red[8];

    float4 x[4];
    float m = -INFINITY;
#pragma unroll
    for (int e = 0; e < 4; e++) {
        x[e] = *(const float4*)&row[t * 4 + 1024 * e];
        m = fmaxf(m, fmaxf(fmaxf(x[e].x, x[e].y), fmaxf(x[e].z, x[e].w)));
    }
#pragma unroll
    for (int o = 32; o; o >>= 1) m = fmaxf(m, __shfl_xor(m, o));
    if (lane == 0) red[wv] = m;
    __syncthreads();
    m = fmaxf(fmaxf(red[0], red[1]), fmaxf(red[2], red[3]));

    float s = 0.f;
#pragma unroll
    for (int e = 0; e < 4; e++) {
        x[e].x = __expf(x[e].x - m); x[e].y = __expf(x[e].y - m);
        x[e].z = __expf(x[e].z - m); x[e].w = __expf(x[e].w - m);
        s += x[e].x + x[e].y + x[e].z + x[e].w;
    }
#pragma unroll
    for (int o = 32; o; o >>= 1) s += __shfl_xor(s, o);
    if (lane == 0) red[4 + wv] = s;
    __syncthreads();
    s = red[4] + red[5] + red[6] + red[7];

    const float inv = 1.0f / s;
#pragma unroll
    for (int e = 0; e < 4; e++) {
        x[e].x *= inv; x[e].y *= inv; x[e].z *= inv; x[e].w *= inv;
        *(float4*)&row[t * 4 + 1024 * e] = x[e];
        ushort4 h;
        h.x = f2b(x[e].x); h.y = f2b(x[e].y);
        h.z = f2b(x[e].z); h.w = f2b(x[e].w);
        *(ushort4*)&rowb[t * 4 + 1024 * e] = h;
    }
}

// ---------------------------------------------------------------------------
// in-place fp32 square transpose (4096x4096 per batch) via 64x64 tile pairs
// ---------------------------------------------------------------------------
__global__ __launch_bounds__(256) void transpose_f32_ip_kernel(float* __restrict__ a)
{
    const int ti = blockIdx.y, tj = blockIdx.x;
    if (tj < ti) return;
    float* base = a + (long)blockIdx.z * NKQ * SEQ;
    __shared__ float ta[64][65];
    __shared__ float tb[64][65];
    const int t = threadIdx.x, r = t >> 4, c = (t & 15) * 4;
    const bool diag = (ti == tj);
#pragma unroll
    for (int e = 0; e < 4; e++) {
        const int rr = r + 16 * e;
        const float4 va = *(const float4*)&base[(long)(ti * 64 + rr) * 4096 + tj * 64 + c];
        ta[rr][c] = va.x; ta[rr][c + 1] = va.y; ta[rr][c + 2] = va.z; ta[rr][c + 3] = va.w;
        if (!diag) {
            const float4 vb = *(const float4*)&base[(long)(tj * 64 + rr) * 4096 + ti * 64 + c];
            tb[rr][c] = vb.x; tb[rr][c + 1] = vb.y; tb[rr][c + 2] = vb.z; tb[rr][c + 3] = vb.w;
        }
    }
    __syncthreads();
#pragma unroll
    for (int e = 0; e < 4; e++) {
        const int rr = r + 16 * e;
        float4 w;
        w.x = ta[c][rr]; w.y = ta[c + 1][rr]; w.z = ta[c + 2][rr]; w.w = ta[c + 3][rr];
        *(float4*)&base[(long)(tj * 64 + rr) * 4096 + ti * 64 + c] = w;
        if (!diag) {
            float4 u;
            u.x = tb[c][rr]; u.y = tb[c + 1][rr]; u.z = tb[c + 2][rr]; u.w = tb[c + 3][rr];
            *(float4*)&base[(long)(ti * 64 + rr) * 4096 + tj * 64 + c] = u;
        }
    }
}

// ---------------------------------------------------------------------------
extern "C" void kernel_launch(void* const* d_in, const int* in_sizes, int n_in,
                              void* d_out, int out_size, void* d_ws, size_t ws_size,
                              hipStream_t stream)
{
    const float* queries = (const float*)d_in[0];
    const float* keys    = (const float*)d_in[1];
    const float* values  = (const float*)d_in[2];
    const float* Wq = (const float*)d_in[3]; const float* bq = (const float*)d_in[4];
    const float* Wk = (const float*)d_in[5]; const float* bk = (const float*)d_in[6];
    const float* Wv = (const float*)d_in[7]; const float* bv = (const float*)d_in[8];

    float* ctx  = (float*)d_out;                       // [B][KQ][H]
    float* attn = ctx + (long)NBATCH * NKQ * HIDDEN;   // [B][KQ][S] then transposed in place

    // Workspace layout (160 MB total):
    //   [0,32)    vT_b   [B][H][S] bf16         (live through PV)
    //   [32,64)   q_b    [B][KQ][H] bf16        (dead after QK^T)
    //   [64,96)   k_b    [B][S][H] bf16         (dead after QK^T)
    //   [96,128)  v_b    [B][S][H] bf16         (dead after transpose_b)
    //   [128,134) Wqb/Wkb/Wvb bf16              (dead after projections)
    //   [32,160)  attn_b [B][KQ][S] bf16        (written by softmax; aliases
    //             q_b/k_b/v_b/W*b, all dead by then)
    char* ws = (char*)d_ws;
    us* vT_b = (us*)(ws);
    us* q_b  = (us*)(ws + (size_t)32  * 1024 * 1024);
    us* k_b  = (us*)(ws + (size_t)64  * 1024 * 1024);
    us* v_b  = (us*)(ws + (size_t)96  * 1024 * 1024);
    us* Wqb  = (us*)(ws + (size_t)128 * 1024 * 1024);
    us* Wkb  = Wqb + (size_t)HIDDEN * HIDDEN;
    us* Wvb  = Wkb + (size_t)HIDDEN * HIDDEN;
    us* attn_b = (us*)(ws + (size_t)32 * 1024 * 1024);

    const dim3 blk(256);
    const dim3 blk2(512);
    const int nW = HIDDEN * HIDDEN;

    // weights -> bf16
    f2b_kernel<<<dim3(nW / 1024), blk, 0, stream>>>(Wq, Wqb, nW);
    f2b_kernel<<<dim3(nW / 1024), blk, 0, stream>>>(Wk, Wkb, nW);
    f2b_kernel<<<dim3(nW / 1024), blk, 0, stream>>>(Wv, Wvb, nW);

    // projections: [16384 x 1024] = fp32 in @ bf16 W^T + bias -> bf16
    gemm_nt<true, true, true, true><<<dim3(HIDDEN / 128, (NBATCH * NKQ) / 128, 1), blk, 0, stream>>>(
        queries, Wqb, bq, q_b, NBATCH * NKQ, HIDDEN, HIDDEN, 0, 0, 0, 1.0f);
    gemm_nt<true, true, true, true><<<dim3(HIDDEN / 128, (NBATCH * SEQ) / 128, 1), blk, 0, stream>>>(
        keys, Wkb, bk, k_b, NBATCH * SEQ, HIDDEN, HIDDEN, 0, 0, 0, 1.0f);
    gemm_nt<true, true, true, true><<<dim3(HIDDEN / 128, (NBATCH * SEQ) / 128, 1), blk, 0, stream>>>(
        values, Wvb, bv, v_b, NBATCH * SEQ, HIDDEN, HIDDEN, 0, 0, 0, 1.0f);

    // v_b [S][H] -> vT_b [H][S]
    transpose_b_kernel<<<dim3(HIDDEN / 64, SEQ / 64, NBATCH), blk, 0, stream>>>(v_b, vT_b);

    // scoresT[b][kq][s] = (1/32) * q_b[kq,:] . k_b[s,:]  -> attn region (fp32)
    gemm_nt_256<<<dim3(SEQ / 256, NKQ / 256, NBATCH), blk2, 0, stream>>>(
        q_b, k_b, attn, NKQ, SEQ, HIDDEN,
        (long)NKQ * HIDDEN, (long)SEQ * HIDDEN, (long)NKQ * SEQ, 0.03125f);

    // softmax over s (contiguous rows): fp32 in place + bf16 copy for PV
    softmax_rows_kernel<<<dim3(NKQ, NBATCH), blk, 0, stream>>>(attn, attn_b);

    // context[b][kq][h] = sum_s attn_b[kq,s] * vT_b[h,s]
    gemm_nt_256<<<dim3(HIDDEN / 256, NKQ / 256, NBATCH), blk2, 0, stream>>>(
        attn_b, vT_b, ctx, NKQ, HIDDEN, SEQ,
        (long)NKQ * SEQ, (long)HIDDEN * SEQ, (long)NKQ * HIDDEN, 1.0f);

    // attn [B][KQ][S] -> [B][S][KQ] in place
    transpose_f32_ip_kernel<<<dim3(64, 64, NBATCH), blk, 0, stream>>>(attn);
}